// Round 1
// baseline (443.597 us; speedup 1.0000x reference)
//
#include <hip/hip_runtime.h>

#define BB 512
#define TTOK 196
#define DD 256
#define TCHUNK 14
#define NCHUNK 14

typedef __attribute__((ext_vector_type(8))) __bf16 bf16x8;
typedef __attribute__((ext_vector_type(4))) float floatx4;

__device__ __forceinline__ unsigned short f2bf(float f) {
  unsigned int u = __float_as_uint(f);
  u += 0x7FFFu + ((u >> 16) & 1u);   // round-to-nearest-even
  return (unsigned short)(u >> 16);
}

// Kernel 1: per-token L2-normalize, cast to bf16, transpose [B,T,D]->[T,B,D].
// Block (64,4): one wave per token, 4 tokens per block.
__global__ __launch_bounds__(256) void k_norm(const float* __restrict__ in,
                                              unsigned short* __restrict__ out) {
  int u = blockIdx.x * 4 + threadIdx.y;   // token id = b*TTOK + t
  int lane = threadIdx.x;                 // 0..63
  int b = u / TTOK;
  int t = u - b * TTOK;
  float4 v = *((const float4*)(in + (size_t)u * DD) + lane);
  float ss = v.x * v.x + v.y * v.y + v.z * v.z + v.w * v.w;
#pragma unroll
  for (int off = 32; off; off >>= 1) ss += __shfl_xor(ss, off, 64);
  float inv = ss > 1e-24f ? 1.0f / sqrtf(ss) : 0.0f;
  ushort4 o;
  o.x = f2bf(v.x * inv);
  o.y = f2bf(v.y * inv);
  o.z = f2bf(v.z * inv);
  o.w = f2bf(v.w * inv);
  *((ushort4*)(out + ((size_t)t * BB + b) * DD) + lane) = o;
}

// Kernel 2: fused per-t GEMM (cos = An_t @ Vn_t^T) + softmax-pool partial sums.
// Grid (8,8,NCHUNK); block 256 = 4 waves in 2x2; each wave owns a 32x32 (b,c)
// subtile via 2x2 mfma_f32_16x16x32_bf16. Fixed-shift softmax: s += e^(c-1),
// w += c*e^(c-1), accumulated over this chunk's 14 t values.
__global__ __launch_bounds__(256) void k_gemm_pool(
    const unsigned short* __restrict__ An, const unsigned short* __restrict__ Vn,
    float2* __restrict__ partial) {
  int wave = threadIdx.x >> 6;
  int lane = threadIdx.x & 63;
  int wr = wave >> 1, wc = wave & 1;
  int row0 = blockIdx.x * 64 + wr * 32;   // text rows (b)
  int col0 = blockIdx.y * 64 + wc * 32;   // visual rows (c)
  int t0 = blockIdx.z * TCHUNK;
  int lm = lane & 15;
  int lk = (lane >> 4) * 8;

  unsigned aoff0 = (unsigned)(row0 + lm) * DD + lk;
  unsigned aoff1 = aoff0 + 16u * DD;
  unsigned boff0 = (unsigned)(col0 + lm) * DD + lk;
  unsigned boff1 = boff0 + 16u * DD;

  floatx4 s[2][2], w[2][2];
#pragma unroll
  for (int i = 0; i < 2; i++)
#pragma unroll
    for (int j = 0; j < 2; j++) {
      s[i][j] = (floatx4){0.f, 0.f, 0.f, 0.f};
      w[i][j] = (floatx4){0.f, 0.f, 0.f, 0.f};
    }

  for (int tt = 0; tt < TCHUNK; ++tt) {
    const unsigned short* A = An + (size_t)(t0 + tt) * (BB * DD);
    const unsigned short* V = Vn + (size_t)(t0 + tt) * (BB * DD);
    floatx4 acc[2][2];
#pragma unroll
    for (int i = 0; i < 2; i++)
#pragma unroll
      for (int j = 0; j < 2; j++) acc[i][j] = (floatx4){0.f, 0.f, 0.f, 0.f};
#pragma unroll
    for (int k0 = 0; k0 < DD; k0 += 32) {
      bf16x8 a0 = *(const bf16x8*)(A + aoff0 + k0);
      bf16x8 a1 = *(const bf16x8*)(A + aoff1 + k0);
      bf16x8 b0 = *(const bf16x8*)(V + boff0 + k0);
      bf16x8 b1 = *(const bf16x8*)(V + boff1 + k0);
      acc[0][0] = __builtin_amdgcn_mfma_f32_16x16x32_bf16(a0, b0, acc[0][0], 0, 0, 0);
      acc[0][1] = __builtin_amdgcn_mfma_f32_16x16x32_bf16(a0, b1, acc[0][1], 0, 0, 0);
      acc[1][0] = __builtin_amdgcn_mfma_f32_16x16x32_bf16(a1, b0, acc[1][0], 0, 0, 0);
      acc[1][1] = __builtin_amdgcn_mfma_f32_16x16x32_bf16(a1, b1, acc[1][1], 0, 0, 0);
    }
#pragma unroll
    for (int mi = 0; mi < 2; mi++)
#pragma unroll
      for (int ni = 0; ni < 2; ni++)
#pragma unroll
        for (int r = 0; r < 4; r++) {
          float c = acc[mi][ni][r];
          float e = __expf(c - 1.0f);
          s[mi][ni][r] += e;
          w[mi][ni][r] += c * e;
        }
  }
  // C/D layout (m89-verified): col = lane&15, row = (lane>>4)*4 + r
  size_t cb = (size_t)blockIdx.z * (BB * BB);
#pragma unroll
  for (int mi = 0; mi < 2; mi++)
#pragma unroll
    for (int ni = 0; ni < 2; ni++)
#pragma unroll
      for (int r = 0; r < 4; r++) {
        int bi = row0 + mi * 16 + (lane >> 4) * 4 + r;
        int ci = col0 + ni * 16 + lm;
        partial[cb + (size_t)bi * BB + ci] = make_float2(s[mi][ni][r], w[mi][ni][r]);
      }
}

// Kernel 3: merge chunk partials -> logits = (w/s)/TEMPERATURE
__global__ __launch_bounds__(256) void k_merge(const float2* __restrict__ partial,
                                               float* __restrict__ logits) {
  int idx = blockIdx.x * 256 + threadIdx.x;
  float s = 0.f, w = 0.f;
#pragma unroll
  for (int ch = 0; ch < NCHUNK; ++ch) {
    float2 p = partial[(size_t)ch * (BB * BB) + idx];
    s += p.x;
    w += p.y;
  }
  logits[idx] = (w / s) * (1.0f / 0.07f);
}

// Kernel 4: per-b row-LSE and col-LSE of logits; contrib[b] = 2*L[b,b]-lse_r-lse_c
__global__ __launch_bounds__(256) void k_lse(const float* __restrict__ logits,
                                             float* __restrict__ contrib) {
  int b = blockIdx.x;
  int tid = threadIdx.x;
  __shared__ float sm[4];

  float r0 = logits[(size_t)b * BB + tid];
  float r1 = logits[(size_t)b * BB + tid + 256];
  float c0 = logits[(size_t)tid * BB + b];
  float c1 = logits[((size_t)tid + 256) * BB + b];

  // row max
  float v = fmaxf(r0, r1);
#pragma unroll
  for (int off = 32; off; off >>= 1) v = fmaxf(v, __shfl_xor(v, off, 64));
  if ((tid & 63) == 0) sm[tid >> 6] = v;
  __syncthreads();
  float mr = fmaxf(fmaxf(sm[0], sm[1]), fmaxf(sm[2], sm[3]));
  __syncthreads();
  // row sum-exp
  v = __expf(r0 - mr) + __expf(r1 - mr);
#pragma unroll
  for (int off = 32; off; off >>= 1) v += __shfl_xor(v, off, 64);
  if ((tid & 63) == 0) sm[tid >> 6] = v;
  __syncthreads();
  float sr = sm[0] + sm[1] + sm[2] + sm[3];
  __syncthreads();
  // col max
  v = fmaxf(c0, c1);
#pragma unroll
  for (int off = 32; off; off >>= 1) v = fmaxf(v, __shfl_xor(v, off, 64));
  if ((tid & 63) == 0) sm[tid >> 6] = v;
  __syncthreads();
  float mc = fmaxf(fmaxf(sm[0], sm[1]), fmaxf(sm[2], sm[3]));
  __syncthreads();
  // col sum-exp
  v = __expf(c0 - mc) + __expf(c1 - mc);
#pragma unroll
  for (int off = 32; off; off >>= 1) v += __shfl_xor(v, off, 64);
  if ((tid & 63) == 0) sm[tid >> 6] = v;
  __syncthreads();
  float sc = sm[0] + sm[1] + sm[2] + sm[3];

  if (tid == 0) {
    float diag = logits[(size_t)b * BB + b];
    contrib[b] = 2.f * diag - (mr + logf(sr)) - (mc + logf(sc));
  }
}

// Kernel 5: loss = -(1/1024) * sum_b contrib[b]
__global__ __launch_bounds__(256) void k_final(const float* __restrict__ contrib,
                                               float* __restrict__ out) {
  int tid = threadIdx.x;
  float v = contrib[tid] + contrib[tid + 256];
#pragma unroll
  for (int off = 32; off; off >>= 1) v += __shfl_xor(v, off, 64);
  __shared__ float sm[4];
  if ((tid & 63) == 0) sm[tid >> 6] = v;
  __syncthreads();
  if (tid == 0) out[0] = -(sm[0] + sm[1] + sm[2] + sm[3]) * (1.0f / 1024.0f);
}

extern "C" void kernel_launch(void* const* d_in, const int* in_sizes, int n_in,
                              void* d_out, int out_size, void* d_ws, size_t ws_size,
                              hipStream_t stream) {
  const float* text = (const float*)d_in[0];
  const float* visual = (const float*)d_in[1];

  char* ws = (char*)d_ws;
  const size_t szN = (size_t)TTOK * BB * DD * sizeof(unsigned short);   // 51,380,224 B
  const size_t szP = (size_t)NCHUNK * BB * BB * sizeof(float2);         // 29,360,128 B
  unsigned short* An = (unsigned short*)ws;
  unsigned short* Vn = (unsigned short*)(ws + szN);
  float2* partial = (float2*)(ws + 2 * szN);
  float* logits = (float*)(ws + 2 * szN + szP);
  float* contrib = (float*)(ws + 2 * szN + szP + (size_t)BB * BB * sizeof(float));

  dim3 blk1(64, 4);
  k_norm<<<BB * TTOK / 4, blk1, 0, stream>>>(text, An);
  k_norm<<<BB * TTOK / 4, blk1, 0, stream>>>(visual, Vn);
  k_gemm_pool<<<dim3(8, 8, NCHUNK), 256, 0, stream>>>(An, Vn, partial);
  k_merge<<<BB * BB / 256, 256, 0, stream>>>(partial, logits);
  k_lse<<<BB, 256, 0, stream>>>(logits, contrib);
  k_final<<<1, 256, 0, stream>>>(contrib, (float*)d_out);
}

// Round 2
// 421.808 us; speedup vs baseline: 1.0517x; 1.0517x over previous
//
#include <hip/hip_runtime.h>

#define BB 512
#define TTOK 196
#define DD 256
#define TCHUNK 14
#define NCHUNK 14

typedef __attribute__((ext_vector_type(8))) __bf16 bf16x8;
typedef __attribute__((ext_vector_type(4))) float floatx4;

__device__ __forceinline__ unsigned short f2bf(float f) {
  unsigned int u = __float_as_uint(f);
  u += 0x7FFFu + ((u >> 16) & 1u);   // round-to-nearest-even
  return (unsigned short)(u >> 16);
}

// Kernel 1: per-token L2-normalize, cast to bf16, transpose [B,T,D]->[T,B,D].
// Both tensors in one launch (blockIdx.y selects). One wave per token.
__global__ __launch_bounds__(256) void k_norm2(const float* __restrict__ text,
                                               const float* __restrict__ visual,
                                               unsigned short* __restrict__ An,
                                               unsigned short* __restrict__ Vn) {
  const float* in = blockIdx.y ? visual : text;
  unsigned short* out = blockIdx.y ? Vn : An;
  int u = blockIdx.x * 4 + threadIdx.y;   // token id = b*TTOK + t
  int lane = threadIdx.x;                 // 0..63
  int b = u / TTOK;
  int t = u - b * TTOK;
  float4 v = *((const float4*)(in + (size_t)u * DD) + lane);
  float ss = v.x * v.x + v.y * v.y + v.z * v.z + v.w * v.w;
#pragma unroll
  for (int off = 32; off; off >>= 1) ss += __shfl_xor(ss, off, 64);
  float inv = ss > 1e-24f ? 1.0f / sqrtf(ss) : 0.0f;
  ushort4 o;
  o.x = f2bf(v.x * inv);
  o.y = f2bf(v.y * inv);
  o.z = f2bf(v.z * inv);
  o.w = f2bf(v.w * inv);
  *((ushort4*)(out + ((size_t)t * BB + b) * DD) + lane) = o;
}

// Kernel 2: fused per-t GEMM (cos = An_t @ Vn_t^T) + softmax-pool partials.
// Grid (8,8,NCHUNK); 4 waves in 2x2; wave = 32x32 (b,c) via 2x2 16x16x32 MFMA.
// Flattened (t, k64) loop with one-stage register prefetch: while 8 MFMAs
// consume the current 64-k panel, the next panel's 8 bf16x8 loads are in
// flight. __launch_bounds__(256,3): cap ~170 VGPR -> 3 blocks/CU, 12 waves/CU.
__global__ __launch_bounds__(256, 3) void k_gemm_pool(
    const unsigned short* __restrict__ An, const unsigned short* __restrict__ Vn,
    float2* __restrict__ partial) {
  int wave = threadIdx.x >> 6;
  int lane = threadIdx.x & 63;
  int wr = wave >> 1, wc = wave & 1;
  int row0 = blockIdx.x * 64 + wr * 32;   // text rows (b)
  int col0 = blockIdx.y * 64 + wc * 32;   // visual rows (c)
  int t0 = blockIdx.z * TCHUNK;
  int lm = lane & 15;
  int lk = (lane >> 4) * 8;

  const unsigned aoff0 = (unsigned)(row0 + lm) * DD + lk;
  const unsigned aoff1 = aoff0 + 16u * DD;
  const unsigned boff0 = (unsigned)(col0 + lm) * DD + lk;
  const unsigned boff1 = boff0 + 16u * DD;

  const unsigned short* Ab = An + (size_t)t0 * (BB * DD);
  const unsigned short* Vb = Vn + (size_t)t0 * (BB * DD);

  floatx4 s[2][2], w[2][2], acc[2][2];
#pragma unroll
  for (int i = 0; i < 2; i++)
#pragma unroll
    for (int j = 0; j < 2; j++) {
      s[i][j] = (floatx4){0.f, 0.f, 0.f, 0.f};
      w[i][j] = (floatx4){0.f, 0.f, 0.f, 0.f};
      acc[i][j] = (floatx4){0.f, 0.f, 0.f, 0.f};
    }

  // current-panel regs (k64 = two 32-k subchunks)
  bf16x8 ca00, ca01, ca10, ca11, cb00, cb01, cb10, cb11;
  {
    ca00 = *(const bf16x8*)(Ab + aoff0);
    ca01 = *(const bf16x8*)(Ab + aoff0 + 32);
    ca10 = *(const bf16x8*)(Ab + aoff1);
    ca11 = *(const bf16x8*)(Ab + aoff1 + 32);
    cb00 = *(const bf16x8*)(Vb + boff0);
    cb01 = *(const bf16x8*)(Vb + boff0 + 32);
    cb10 = *(const bf16x8*)(Vb + boff1);
    cb11 = *(const bf16x8*)(Vb + boff1 + 32);
  }

  const int NIT = TCHUNK * 4;  // 4 k64-panels per t
  for (int it = 0; it < NIT; ++it) {
    bf16x8 na00, na01, na10, na11, nb00, nb01, nb10, nb11;
    int nit = it + 1;
    if (nit < NIT) {
      const unsigned short* A = Ab + (size_t)(nit >> 2) * (BB * DD);
      const unsigned short* V = Vb + (size_t)(nit >> 2) * (BB * DD);
      unsigned nk = (unsigned)(nit & 3) * 64u;
      na00 = *(const bf16x8*)(A + aoff0 + nk);
      na01 = *(const bf16x8*)(A + aoff0 + nk + 32);
      na10 = *(const bf16x8*)(A + aoff1 + nk);
      na11 = *(const bf16x8*)(A + aoff1 + nk + 32);
      nb00 = *(const bf16x8*)(V + boff0 + nk);
      nb01 = *(const bf16x8*)(V + boff0 + nk + 32);
      nb10 = *(const bf16x8*)(V + boff1 + nk);
      nb11 = *(const bf16x8*)(V + boff1 + nk + 32);
    }
    acc[0][0] = __builtin_amdgcn_mfma_f32_16x16x32_bf16(ca00, cb00, acc[0][0], 0, 0, 0);
    acc[0][1] = __builtin_amdgcn_mfma_f32_16x16x32_bf16(ca00, cb10, acc[0][1], 0, 0, 0);
    acc[1][0] = __builtin_amdgcn_mfma_f32_16x16x32_bf16(ca10, cb00, acc[1][0], 0, 0, 0);
    acc[1][1] = __builtin_amdgcn_mfma_f32_16x16x32_bf16(ca10, cb10, acc[1][1], 0, 0, 0);
    acc[0][0] = __builtin_amdgcn_mfma_f32_16x16x32_bf16(ca01, cb01, acc[0][0], 0, 0, 0);
    acc[0][1] = __builtin_amdgcn_mfma_f32_16x16x32_bf16(ca01, cb11, acc[0][1], 0, 0, 0);
    acc[1][0] = __builtin_amdgcn_mfma_f32_16x16x32_bf16(ca11, cb01, acc[1][0], 0, 0, 0);
    acc[1][1] = __builtin_amdgcn_mfma_f32_16x16x32_bf16(ca11, cb11, acc[1][1], 0, 0, 0);

    if ((it & 3) == 3) {  // end of one t: fold cos tile into pool sums
#pragma unroll
      for (int mi = 0; mi < 2; mi++)
#pragma unroll
        for (int ni = 0; ni < 2; ni++) {
#pragma unroll
          for (int r = 0; r < 4; r++) {
            float c = acc[mi][ni][r];
            float e = __expf(c - 1.0f);
            s[mi][ni][r] += e;
            w[mi][ni][r] = fmaf(c, e, w[mi][ni][r]);
          }
          acc[mi][ni] = (floatx4){0.f, 0.f, 0.f, 0.f};
        }
    }
    ca00 = na00; ca01 = na01; ca10 = na10; ca11 = na11;
    cb00 = nb00; cb01 = nb01; cb10 = nb10; cb11 = nb11;
  }

  // C/D layout (m89-verified): col = lane&15, row = (lane>>4)*4 + r
  size_t cb = (size_t)blockIdx.z * (BB * BB);
#pragma unroll
  for (int mi = 0; mi < 2; mi++)
#pragma unroll
    for (int ni = 0; ni < 2; ni++)
#pragma unroll
      for (int r = 0; r < 4; r++) {
        int bi = row0 + mi * 16 + (lane >> 4) * 4 + r;
        int ci = col0 + ni * 16 + lm;
        partial[cb + (size_t)bi * BB + ci] = make_float2(s[mi][ni][r], w[mi][ni][r]);
      }
}

// Kernel 3: merge chunk partials -> logits = (w/s)/TEMPERATURE
__global__ __launch_bounds__(256) void k_merge(const float2* __restrict__ partial,
                                               float* __restrict__ logits) {
  int idx = blockIdx.x * 256 + threadIdx.x;
  float s = 0.f, w = 0.f;
#pragma unroll
  for (int ch = 0; ch < NCHUNK; ++ch) {
    float2 p = partial[(size_t)ch * (BB * BB) + idx];
    s += p.x;
    w += p.y;
  }
  logits[idx] = (w / s) * (1.0f / 0.07f);
}

// Kernel 4: per-b row-LSE and col-LSE of logits; contrib[b]=2*L[b,b]-lse_r-lse_c
__global__ __launch_bounds__(256) void k_lse(const float* __restrict__ logits,
                                             float* __restrict__ contrib) {
  int b = blockIdx.x;
  int tid = threadIdx.x;
  __shared__ float sm[4];

  float r0 = logits[(size_t)b * BB + tid];
  float r1 = logits[(size_t)b * BB + tid + 256];
  float c0 = logits[(size_t)tid * BB + b];
  float c1 = logits[((size_t)tid + 256) * BB + b];

  float v = fmaxf(r0, r1);
#pragma unroll
  for (int off = 32; off; off >>= 1) v = fmaxf(v, __shfl_xor(v, off, 64));
  if ((tid & 63) == 0) sm[tid >> 6] = v;
  __syncthreads();
  float mr = fmaxf(fmaxf(sm[0], sm[1]), fmaxf(sm[2], sm[3]));
  __syncthreads();
  v = __expf(r0 - mr) + __expf(r1 - mr);
#pragma unroll
  for (int off = 32; off; off >>= 1) v += __shfl_xor(v, off, 64);
  if ((tid & 63) == 0) sm[tid >> 6] = v;
  __syncthreads();
  float sr = sm[0] + sm[1] + sm[2] + sm[3];
  __syncthreads();
  v = fmaxf(c0, c1);
#pragma unroll
  for (int off = 32; off; off >>= 1) v = fmaxf(v, __shfl_xor(v, off, 64));
  if ((tid & 63) == 0) sm[tid >> 6] = v;
  __syncthreads();
  float mc = fmaxf(fmaxf(sm[0], sm[1]), fmaxf(sm[2], sm[3]));
  __syncthreads();
  v = __expf(c0 - mc) + __expf(c1 - mc);
#pragma unroll
  for (int off = 32; off; off >>= 1) v += __shfl_xor(v, off, 64);
  if ((tid & 63) == 0) sm[tid >> 6] = v;
  __syncthreads();
  float sc = sm[0] + sm[1] + sm[2] + sm[3];

  if (tid == 0) {
    float diag = logits[(size_t)b * BB + b];
    contrib[b] = 2.f * diag - (mr + logf(sr)) - (mc + logf(sc));
  }
}

// Kernel 5: loss = -(1/1024) * sum_b contrib[b]
__global__ __launch_bounds__(256) void k_final(const float* __restrict__ contrib,
                                               float* __restrict__ out) {
  int tid = threadIdx.x;
  float v = contrib[tid] + contrib[tid + 256];
#pragma unroll
  for (int off = 32; off; off >>= 1) v += __shfl_xor(v, off, 64);
  __shared__ float sm[4];
  if ((tid & 63) == 0) sm[tid >> 6] = v;
  __syncthreads();
  if (tid == 0) out[0] = -(sm[0] + sm[1] + sm[2] + sm[3]) * (1.0f / 1024.0f);
}

extern "C" void kernel_launch(void* const* d_in, const int* in_sizes, int n_in,
                              void* d_out, int out_size, void* d_ws, size_t ws_size,
                              hipStream_t stream) {
  const float* text = (const float*)d_in[0];
  const float* visual = (const float*)d_in[1];

  char* ws = (char*)d_ws;
  const size_t szN = (size_t)TTOK * BB * DD * sizeof(unsigned short);   // 51,380,224 B
  const size_t szP = (size_t)NCHUNK * BB * BB * sizeof(float2);         // 29,360,128 B
  unsigned short* An = (unsigned short*)ws;
  unsigned short* Vn = (unsigned short*)(ws + szN);
  float2* partial = (float2*)(ws + 2 * szN);
  float* logits = (float*)(ws + 2 * szN + szP);
  float* contrib = (float*)(ws + 2 * szN + szP + (size_t)BB * BB * sizeof(float));

  dim3 blk1(64, 4);
  k_norm2<<<dim3(BB * TTOK / 4, 2), blk1, 0, stream>>>(text, visual, An, Vn);
  k_gemm_pool<<<dim3(8, 8, NCHUNK), 256, 0, stream>>>(An, Vn, partial);
  k_merge<<<BB * BB / 256, 256, 0, stream>>>(partial, logits);
  k_lse<<<BB, 256, 0, stream>>>(logits, contrib);
  k_final<<<1, 256, 0, stream>>>(contrib, (float*)d_out);
}

// Round 3
// 366.314 us; speedup vs baseline: 1.2110x; 1.1515x over previous
//
#include <hip/hip_runtime.h>

#define BB 512
#define TTOK 196
#define DD 256
#define TCHUNK 7
#define NCHUNK 28          // 196 / 7
#define BM 128             // block tile (b and c)
#define BK 64              // k elements per stage
#define NSTAGE (TCHUNK * 4)  // 4 k-stages per t

typedef __attribute__((ext_vector_type(8))) __bf16 bf16x8;
typedef __attribute__((ext_vector_type(4))) float floatx4;
typedef __attribute__((address_space(3))) char* lds_t;
typedef const __attribute__((address_space(1))) void* gas_t;

__device__ __forceinline__ unsigned short f2bf(float f) {
  unsigned int u = __float_as_uint(f);
  u += 0x7FFFu + ((u >> 16) & 1u);   // round-to-nearest-even
  return (unsigned short)(u >> 16);
}

// Kernel 1: per-token L2-normalize, cast to bf16, transpose [B,T,D]->[T,B,D].
// Both tensors in one launch (blockIdx.y selects). One wave per token.
__global__ __launch_bounds__(256) void k_norm2(const float* __restrict__ text,
                                               const float* __restrict__ visual,
                                               unsigned short* __restrict__ An,
                                               unsigned short* __restrict__ Vn) {
  const float* in = blockIdx.y ? visual : text;
  unsigned short* out = blockIdx.y ? Vn : An;
  int u = blockIdx.x * 4 + threadIdx.y;   // token id = b*TTOK + t
  int lane = threadIdx.x;                 // 0..63
  int b = u / TTOK;
  int t = u - b * TTOK;
  float4 v = *((const float4*)(in + (size_t)u * DD) + lane);
  float ss = v.x * v.x + v.y * v.y + v.z * v.z + v.w * v.w;
#pragma unroll
  for (int off = 32; off; off >>= 1) ss += __shfl_xor(ss, off, 64);
  float inv = ss > 1e-24f ? 1.0f / sqrtf(ss) : 0.0f;
  ushort4 o;
  o.x = f2bf(v.x * inv);
  o.y = f2bf(v.y * inv);
  o.z = f2bf(v.z * inv);
  o.w = f2bf(v.w * inv);
  *((ushort4*)(out + ((size_t)t * BB + b) * DD) + lane) = o;
}

// Kernel 2: m97-style fused GEMM+pool. Grid (4,4,NCHUNK); 256 thr = 4 waves
// (2x2), wave tile 64x64 via 4x4 x mfma_f32_16x16x32_bf16. Per stage (one
// BK=64 k-slice of one t): A-tile 128x64 + B-tile 128x64 staged to LDS with
// global_load_lds width=16, double-buffered (4x16KB = 64KB). Source-side XOR
// granule swizzle (slot p holds granule p^(r&7)) keeps LDS stores linear
// (m104 caveat) while ds_read_b128 lands 2-way-conflict-only (free, m136).
// One barrier per stage: its vmcnt(0) drain targets loads issued one full
// compute phase earlier. Pool folds per t; (s,w) atomically added to accbuf.
__global__ __launch_bounds__(256, 2) void k_gemm_pool(
    const unsigned short* __restrict__ An, const unsigned short* __restrict__ Vn,
    float* __restrict__ accbuf) {
  __shared__ char smem[65536];
  const int tid = threadIdx.x;
  const int wave = tid >> 6, lane = tid & 63;
  const int wr = wave >> 1, wc = wave & 1;
  const int lm = lane & 15, quad = lane >> 4, l7 = lane & 7;
  const int row_base = blockIdx.x * BM;
  const int col_base = blockIdx.y * BM;
  const int t0 = blockIdx.z * TCHUNK;

  // Staging source offsets (in elements) for 4 rounds per tensor.
  // Linear LDS slot s = q*256+tid -> row r = s>>3, slot-granule p = s&7,
  // which must receive global granule g = p ^ (r&7) (8 bf16 = 16B).
  unsigned aoffs[4], boffs[4];
#pragma unroll
  for (int q = 0; q < 4; q++) {
    int s = q * 256 + tid;
    int r = s >> 3;
    int g = (s & 7) ^ (r & 7);
    aoffs[q] = (unsigned)(row_base + r) * DD + (unsigned)g * 8;
    boffs[q] = (unsigned)(col_base + r) * DD + (unsigned)g * 8;
  }
  lds_t lds = (lds_t)smem;
  const unsigned ldsoff = (unsigned)tid * 16u;

  // Fragment row byte-offsets within a tile (row stride = BK*2 = 128B).
  unsigned aRow[4], bRow[4];
#pragma unroll
  for (int i = 0; i < 4; i++) {
    aRow[i] = (unsigned)(wr * 64 + i * 16 + lm) * 128u;
    bRow[i] = (unsigned)(wc * 64 + i * 16 + lm) * 128u;
  }

  floatx4 acc[4][4], sacc[4][4], wacc[4][4];
#pragma unroll
  for (int i = 0; i < 4; i++)
#pragma unroll
    for (int j = 0; j < 4; j++) {
      acc[i][j] = (floatx4){0.f, 0.f, 0.f, 0.f};
      sacc[i][j] = (floatx4){0.f, 0.f, 0.f, 0.f};
      wacc[i][j] = (floatx4){0.f, 0.f, 0.f, 0.f};
    }

  auto issue = [&](int st, int buf) {
    int t = t0 + (st >> 2);
    unsigned kb = (unsigned)(st & 3) * BK;
    const unsigned short* Ab = An + (size_t)t * (BB * DD) + kb;
    const unsigned short* Bb = Vn + (size_t)t * (BB * DD) + kb;
    unsigned lb = (unsigned)buf * 32768u + ldsoff;
#pragma unroll
    for (int q = 0; q < 4; q++)
      __builtin_amdgcn_global_load_lds((gas_t)(Ab + aoffs[q]),
                                       (__attribute__((address_space(3))) void*)(lds + lb + (unsigned)q * 4096u),
                                       16, 0, 0);
#pragma unroll
    for (int q = 0; q < 4; q++)
      __builtin_amdgcn_global_load_lds((gas_t)(Bb + boffs[q]),
                                       (__attribute__((address_space(3))) void*)(lds + lb + 16384u + (unsigned)q * 4096u),
                                       16, 0, 0);
  };

  issue(0, 0);
  for (int st = 0; st < NSTAGE; ++st) {
    int buf = st & 1;
    __syncthreads();               // drains vmcnt -> buf ready; buf^1 free
    if (st + 1 < NSTAGE) issue(st + 1, buf ^ 1);
    const char* A = smem + buf * 32768;
    const char* B = smem + buf * 32768 + 16384;
#pragma unroll
    for (int k0 = 0; k0 < BK; k0 += 32) {
      unsigned gsw = (unsigned)((((k0 >> 3) + quad) ^ l7)) * 16u;
      bf16x8 a[4], b[4];
#pragma unroll
      for (int mi = 0; mi < 4; mi++) a[mi] = *(const bf16x8*)(A + aRow[mi] + gsw);
#pragma unroll
      for (int ni = 0; ni < 4; ni++) b[ni] = *(const bf16x8*)(B + bRow[ni] + gsw);
#pragma unroll
      for (int mi = 0; mi < 4; mi++)
#pragma unroll
        for (int ni = 0; ni < 4; ni++)
          acc[mi][ni] = __builtin_amdgcn_mfma_f32_16x16x32_bf16(a[mi], b[ni], acc[mi][ni], 0, 0, 0);
    }
    if ((st & 3) == 3) {   // end of one t: fold cos tile into pool sums
#pragma unroll
      for (int mi = 0; mi < 4; mi++)
#pragma unroll
        for (int ni = 0; ni < 4; ni++) {
#pragma unroll
          for (int r = 0; r < 4; r++) {
            float c = acc[mi][ni][r];
            float e = __expf(c - 1.0f);
            sacc[mi][ni][r] += e;
            wacc[mi][ni][r] = fmaf(c, e, wacc[mi][ni][r]);
          }
          acc[mi][ni] = (floatx4){0.f, 0.f, 0.f, 0.f};
        }
    }
  }

  // C/D layout (m89-verified): col = lane&15, row = quad*4 + r
#pragma unroll
  for (int mi = 0; mi < 4; mi++) {
    int bi = row_base + wr * 64 + mi * 16 + quad * 4;
#pragma unroll
    for (int r = 0; r < 4; r++)
#pragma unroll
      for (int ni = 0; ni < 4; ni++) {
        int ci = col_base + wc * 64 + ni * 16 + lm;
        float* p = accbuf + ((size_t)(bi + r) * BB + ci) * 2;
        atomicAdd(p, sacc[mi][ni][r]);
        atomicAdd(p + 1, wacc[mi][ni][r]);
      }
  }
}

// Kernel 3: merged (s,w) -> logits = (w/s)/TEMPERATURE
__global__ __launch_bounds__(256) void k_merge(const float* __restrict__ accbuf,
                                               float* __restrict__ logits) {
  int idx = blockIdx.x * 256 + threadIdx.x;
  float s = accbuf[(size_t)idx * 2];
  float w = accbuf[(size_t)idx * 2 + 1];
  logits[idx] = (w / s) * (1.0f / 0.07f);
}

// Kernel 4: per-b row-LSE and col-LSE of logits; contrib[b]=2*L[b,b]-lse_r-lse_c
__global__ __launch_bounds__(256) void k_lse(const float* __restrict__ logits,
                                             float* __restrict__ contrib) {
  int b = blockIdx.x;
  int tid = threadIdx.x;
  __shared__ float sm[4];

  float r0 = logits[(size_t)b * BB + tid];
  float r1 = logits[(size_t)b * BB + tid + 256];
  float c0 = logits[(size_t)tid * BB + b];
  float c1 = logits[((size_t)tid + 256) * BB + b];

  float v = fmaxf(r0, r1);
#pragma unroll
  for (int off = 32; off; off >>= 1) v = fmaxf(v, __shfl_xor(v, off, 64));
  if ((tid & 63) == 0) sm[tid >> 6] = v;
  __syncthreads();
  float mr = fmaxf(fmaxf(sm[0], sm[1]), fmaxf(sm[2], sm[3]));
  __syncthreads();
  v = __expf(r0 - mr) + __expf(r1 - mr);
#pragma unroll
  for (int off = 32; off; off >>= 1) v += __shfl_xor(v, off, 64);
  if ((tid & 63) == 0) sm[tid >> 6] = v;
  __syncthreads();
  float sr = sm[0] + sm[1] + sm[2] + sm[3];
  __syncthreads();
  v = fmaxf(c0, c1);
#pragma unroll
  for (int off = 32; off; off >>= 1) v = fmaxf(v, __shfl_xor(v, off, 64));
  if ((tid & 63) == 0) sm[tid >> 6] = v;
  __syncthreads();
  float mc = fmaxf(fmaxf(sm[0], sm[1]), fmaxf(sm[2], sm[3]));
  __syncthreads();
  v = __expf(c0 - mc) + __expf(c1 - mc);
#pragma unroll
  for (int off = 32; off; off >>= 1) v += __shfl_xor(v, off, 64);
  if ((tid & 63) == 0) sm[tid >> 6] = v;
  __syncthreads();
  float sc = sm[0] + sm[1] + sm[2] + sm[3];

  if (tid == 0) {
    float diag = logits[(size_t)b * BB + b];
    contrib[b] = 2.f * diag - (mr + logf(sr)) - (mc + logf(sc));
  }
}

// Kernel 5: loss = -(1/1024) * sum_b contrib[b]
__global__ __launch_bounds__(256) void k_final(const float* __restrict__ contrib,
                                               float* __restrict__ out) {
  int tid = threadIdx.x;
  float v = contrib[tid] + contrib[tid + 256];
#pragma unroll
  for (int off = 32; off; off >>= 1) v += __shfl_xor(v, off, 64);
  __shared__ float sm[4];
  if ((tid & 63) == 0) sm[tid >> 6] = v;
  __syncthreads();
  if (tid == 0) out[0] = -(sm[0] + sm[1] + sm[2] + sm[3]) * (1.0f / 1024.0f);
}

extern "C" void kernel_launch(void* const* d_in, const int* in_sizes, int n_in,
                              void* d_out, int out_size, void* d_ws, size_t ws_size,
                              hipStream_t stream) {
  const float* text = (const float*)d_in[0];
  const float* visual = (const float*)d_in[1];

  char* ws = (char*)d_ws;
  const size_t szN = (size_t)TTOK * BB * DD * sizeof(unsigned short);   // 51,380,224 B
  const size_t szA = (size_t)BB * BB * 2 * sizeof(float);               //  2,097,152 B
  unsigned short* An = (unsigned short*)ws;
  unsigned short* Vn = (unsigned short*)(ws + szN);
  float* accbuf = (float*)(ws + 2 * szN);
  float* logits = (float*)(ws + 2 * szN + szA);
  float* contrib = (float*)(ws + 2 * szN + szA + (size_t)BB * BB * sizeof(float));

  hipMemsetAsync(accbuf, 0, szA, stream);
  dim3 blk1(64, 4);
  k_norm2<<<dim3(BB * TTOK / 4, 2), blk1, 0, stream>>>(text, visual, An, Vn);
  k_gemm_pool<<<dim3(4, 4, NCHUNK), 256, 0, stream>>>(An, Vn, accbuf);
  k_merge<<<BB * BB / 256, 256, 0, stream>>>(accbuf, logits);
  k_lse<<<BB, 256, 0, stream>>>(logits, contrib);
  k_final<<<1, 256, 0, stream>>>(contrib, (float*)d_out);
}

// Round 4
// 310.774 us; speedup vs baseline: 1.4274x; 1.1787x over previous
//
#include <hip/hip_runtime.h>

#define BB 512
#define TTOK 196
#define DD 256
#define TCHUNK 14
#define NCHUNK 14          // 196 / 14
#define BM 64              // block tile (b and c)
#define BK 64              // k elements per stage
#define NSTAGE (TCHUNK * 4)  // 4 k-stages per t

typedef __attribute__((ext_vector_type(8))) __bf16 bf16x8;
typedef __attribute__((ext_vector_type(4))) float floatx4;
typedef __attribute__((address_space(3))) char* lds_t;
typedef const __attribute__((address_space(1))) void* gas_t;

__device__ __forceinline__ unsigned short f2bf(float f) {
  unsigned int u = __float_as_uint(f);
  u += 0x7FFFu + ((u >> 16) & 1u);   // round-to-nearest-even
  return (unsigned short)(u >> 16);
}

// Kernel 1: per-token L2-normalize, cast to bf16, transpose [B,T,D]->[T,B,D].
// Both tensors in one launch (blockIdx.y selects). One wave per token.
__global__ __launch_bounds__(256) void k_norm2(const float* __restrict__ text,
                                               const float* __restrict__ visual,
                                               unsigned short* __restrict__ An,
                                               unsigned short* __restrict__ Vn) {
  const float* in = blockIdx.y ? visual : text;
  unsigned short* out = blockIdx.y ? Vn : An;
  int u = blockIdx.x * 4 + threadIdx.y;   // token id = b*TTOK + t
  int lane = threadIdx.x;                 // 0..63
  int b = u / TTOK;
  int t = u - b * TTOK;
  float4 v = *((const float4*)(in + (size_t)u * DD) + lane);
  float ss = v.x * v.x + v.y * v.y + v.z * v.z + v.w * v.w;
#pragma unroll
  for (int off = 32; off; off >>= 1) ss += __shfl_xor(ss, off, 64);
  float inv = ss > 1e-24f ? 1.0f / sqrtf(ss) : 0.0f;
  ushort4 o;
  o.x = f2bf(v.x * inv);
  o.y = f2bf(v.y * inv);
  o.z = f2bf(v.z * inv);
  o.w = f2bf(v.w * inv);
  *((ushort4*)(out + ((size_t)t * BB + b) * DD) + lane) = o;
}

// Kernel 2: fused GEMM+pool. Grid (8,8,NCHUNK); 256 thr = 4 waves (2x2),
// wave tile 32x32 via 2x2 x mfma_f32_16x16x32_bf16. Per stage (BK=64 k-slice
// of one t): A 64x64 + B 64x64 tiles staged via global_load_lds width=16,
// double-buffered (2x16KB = 32KB). Source-side XOR granule swizzle keeps LDS
// stores linear (m104) while ds_read_b128 is 2-way-conflict-only (m136).
// launch_bounds(256,4): <=128 VGPR -> 4 blocks/CU, 16 waves/CU for latency
// hiding across barrier drains. Epilogue: plain float2 partial stores per
// chunk (disjoint tiles, no atomics).
__global__ __launch_bounds__(256, 4) void k_gemm_pool(
    const unsigned short* __restrict__ An, const unsigned short* __restrict__ Vn,
    float2* __restrict__ partial) {
  __shared__ char smem[32768];
  const int tid = threadIdx.x;
  const int wave = tid >> 6, lane = tid & 63;
  const int wr = wave >> 1, wc = wave & 1;
  const int lm = lane & 15, quad = lane >> 4, l7 = lane & 7;
  const int row_base = blockIdx.x * BM;
  const int col_base = blockIdx.y * BM;
  const int t0 = blockIdx.z * TCHUNK;

  // Staging source offsets (elements), 2 granule-rounds per tensor.
  // Linear LDS slot s = q*256+tid -> row r = s>>3 (8 granules/row),
  // slot-granule p = s&7 receives global granule g = p ^ (r&7).
  unsigned aoffs[2], boffs[2];
#pragma unroll
  for (int q = 0; q < 2; q++) {
    int s = q * 256 + tid;
    int r = s >> 3;
    int g = (s & 7) ^ (r & 7);
    aoffs[q] = (unsigned)(row_base + r) * DD + (unsigned)g * 8;
    boffs[q] = (unsigned)(col_base + r) * DD + (unsigned)g * 8;
  }
  lds_t lds = (lds_t)smem;
  const unsigned ldsoff = (unsigned)tid * 16u;

  // Fragment row byte-offsets within a tile (row stride = BK*2 = 128B).
  unsigned aRow[2], bRow[2];
#pragma unroll
  for (int i = 0; i < 2; i++) {
    aRow[i] = (unsigned)(wr * 32 + i * 16 + lm) * 128u;
    bRow[i] = (unsigned)(wc * 32 + i * 16 + lm) * 128u;
  }

  floatx4 acc[2][2], sacc[2][2], wacc[2][2];
#pragma unroll
  for (int i = 0; i < 2; i++)
#pragma unroll
    for (int j = 0; j < 2; j++) {
      acc[i][j] = (floatx4){0.f, 0.f, 0.f, 0.f};
      sacc[i][j] = (floatx4){0.f, 0.f, 0.f, 0.f};
      wacc[i][j] = (floatx4){0.f, 0.f, 0.f, 0.f};
    }

  auto issue = [&](int st, int buf) {
    int t = t0 + (st >> 2);
    unsigned kb = (unsigned)(st & 3) * BK;
    const unsigned short* Ab = An + (size_t)t * (BB * DD) + kb;
    const unsigned short* Bb = Vn + (size_t)t * (BB * DD) + kb;
    unsigned lb = (unsigned)buf * 16384u + ldsoff;
#pragma unroll
    for (int q = 0; q < 2; q++)
      __builtin_amdgcn_global_load_lds((gas_t)(Ab + aoffs[q]),
                                       (__attribute__((address_space(3))) void*)(lds + lb + (unsigned)q * 4096u),
                                       16, 0, 0);
#pragma unroll
    for (int q = 0; q < 2; q++)
      __builtin_amdgcn_global_load_lds((gas_t)(Bb + boffs[q]),
                                       (__attribute__((address_space(3))) void*)(lds + lb + 8192u + (unsigned)q * 4096u),
                                       16, 0, 0);
  };

  issue(0, 0);
  for (int st = 0; st < NSTAGE; ++st) {
    int buf = st & 1;
    __syncthreads();               // drains vmcnt -> buf ready; buf^1 free
    if (st + 1 < NSTAGE) issue(st + 1, buf ^ 1);
    const char* A = smem + buf * 16384;
    const char* B = smem + buf * 16384 + 8192;
#pragma unroll
    for (int k0 = 0; k0 < BK; k0 += 32) {
      unsigned gsw = (unsigned)((((k0 >> 3) + quad) ^ l7)) * 16u;
      bf16x8 a[2], b[2];
#pragma unroll
      for (int mi = 0; mi < 2; mi++) a[mi] = *(const bf16x8*)(A + aRow[mi] + gsw);
#pragma unroll
      for (int ni = 0; ni < 2; ni++) b[ni] = *(const bf16x8*)(B + bRow[ni] + gsw);
#pragma unroll
      for (int mi = 0; mi < 2; mi++)
#pragma unroll
        for (int ni = 0; ni < 2; ni++)
          acc[mi][ni] = __builtin_amdgcn_mfma_f32_16x16x32_bf16(a[mi], b[ni], acc[mi][ni], 0, 0, 0);
    }
    if ((st & 3) == 3) {   // end of one t: fold cos tile into pool sums
#pragma unroll
      for (int mi = 0; mi < 2; mi++)
#pragma unroll
        for (int ni = 0; ni < 2; ni++) {
#pragma unroll
          for (int r = 0; r < 4; r++) {
            float c = acc[mi][ni][r];
            float e = __expf(c - 1.0f);
            sacc[mi][ni][r] += e;
            wacc[mi][ni][r] = fmaf(c, e, wacc[mi][ni][r]);
          }
          acc[mi][ni] = (floatx4){0.f, 0.f, 0.f, 0.f};
        }
    }
  }

  // C/D layout (m89-verified): col = lane&15, row = quad*4 + r
  size_t cb = (size_t)blockIdx.z * (BB * BB);
#pragma unroll
  for (int mi = 0; mi < 2; mi++) {
    int bi = row_base + wr * 32 + mi * 16 + quad * 4;
#pragma unroll
    for (int r = 0; r < 4; r++)
#pragma unroll
      for (int ni = 0; ni < 2; ni++) {
        int ci = col_base + wc * 32 + ni * 16 + lm;
        partial[cb + (size_t)(bi + r) * BB + ci] = make_float2(sacc[mi][ni][r], wacc[mi][ni][r]);
      }
  }
}

// Kernel 3: merge chunk partials -> logits = (w/s)/TEMPERATURE
__global__ __launch_bounds__(256) void k_merge(const float2* __restrict__ partial,
                                               float* __restrict__ logits) {
  int idx = blockIdx.x * 256 + threadIdx.x;
  float s = 0.f, w = 0.f;
#pragma unroll
  for (int ch = 0; ch < NCHUNK; ++ch) {
    float2 p = partial[(size_t)ch * (BB * BB) + idx];
    s += p.x;
    w += p.y;
  }
  logits[idx] = (w / s) * (1.0f / 0.07f);
}

// Kernel 4: per-b row-LSE and col-LSE of logits; contrib[b]=2*L[b,b]-lse_r-lse_c
__global__ __launch_bounds__(256) void k_lse(const float* __restrict__ logits,
                                             float* __restrict__ contrib) {
  int b = blockIdx.x;
  int tid = threadIdx.x;
  __shared__ float sm[4];

  float r0 = logits[(size_t)b * BB + tid];
  float r1 = logits[(size_t)b * BB + tid + 256];
  float c0 = logits[(size_t)tid * BB + b];
  float c1 = logits[((size_t)tid + 256) * BB + b];

  float v = fmaxf(r0, r1);
#pragma unroll
  for (int off = 32; off; off >>= 1) v = fmaxf(v, __shfl_xor(v, off, 64));
  if ((tid & 63) == 0) sm[tid >> 6] = v;
  __syncthreads();
  float mr = fmaxf(fmaxf(sm[0], sm[1]), fmaxf(sm[2], sm[3]));
  __syncthreads();
  v = __expf(r0 - mr) + __expf(r1 - mr);
#pragma unroll
  for (int off = 32; off; off >>= 1) v += __shfl_xor(v, off, 64);
  if ((tid & 63) == 0) sm[tid >> 6] = v;
  __syncthreads();
  float sr = sm[0] + sm[1] + sm[2] + sm[3];
  __syncthreads();
  v = fmaxf(c0, c1);
#pragma unroll
  for (int off = 32; off; off >>= 1) v = fmaxf(v, __shfl_xor(v, off, 64));
  if ((tid & 63) == 0) sm[tid >> 6] = v;
  __syncthreads();
  float mc = fmaxf(fmaxf(sm[0], sm[1]), fmaxf(sm[2], sm[3]));
  __syncthreads();
  v = __expf(c0 - mc) + __expf(c1 - mc);
#pragma unroll
  for (int off = 32; off; off >>= 1) v += __shfl_xor(v, off, 64);
  if ((tid & 63) == 0) sm[tid >> 6] = v;
  __syncthreads();
  float sc = sm[0] + sm[1] + sm[2] + sm[3];

  if (tid == 0) {
    float diag = logits[(size_t)b * BB + b];
    contrib[b] = 2.f * diag - (mr + logf(sr)) - (mc + logf(sc));
  }
}

// Kernel 5: loss = -(1/1024) * sum_b contrib[b]
__global__ __launch_bounds__(256) void k_final(const float* __restrict__ contrib,
                                               float* __restrict__ out) {
  int tid = threadIdx.x;
  float v = contrib[tid] + contrib[tid + 256];
#pragma unroll
  for (int off = 32; off; off >>= 1) v += __shfl_xor(v, off, 64);
  __shared__ float sm[4];
  if ((tid & 63) == 0) sm[tid >> 6] = v;
  __syncthreads();
  if (tid == 0) out[0] = -(sm[0] + sm[1] + sm[2] + sm[3]) * (1.0f / 1024.0f);
}

extern "C" void kernel_launch(void* const* d_in, const int* in_sizes, int n_in,
                              void* d_out, int out_size, void* d_ws, size_t ws_size,
                              hipStream_t stream) {
  const float* text = (const float*)d_in[0];
  const float* visual = (const float*)d_in[1];

  char* ws = (char*)d_ws;
  const size_t szN = (size_t)TTOK * BB * DD * sizeof(unsigned short);   // 51,380,224 B
  const size_t szP = (size_t)NCHUNK * BB * BB * sizeof(float2);         // 29,360,128 B
  unsigned short* An = (unsigned short*)ws;
  unsigned short* Vn = (unsigned short*)(ws + szN);
  float2* partial = (float2*)(ws + 2 * szN);
  float* logits = (float*)(ws + 2 * szN + szP);
  float* contrib = (float*)(ws + 2 * szN + szP + (size_t)BB * BB * sizeof(float));

  dim3 blk1(64, 4);
  k_norm2<<<dim3(BB * TTOK / 4, 2), blk1, 0, stream>>>(text, visual, An, Vn);
  k_gemm_pool<<<dim3(8, 8, NCHUNK), 256, 0, stream>>>(An, Vn, partial);
  k_merge<<<BB * BB / 256, 256, 0, stream>>>(partial, logits);
  k_lse<<<BB, 256, 0, stream>>>(logits, contrib);
  k_final<<<1, 256, 0, stream>>>(contrib, (float*)d_out);
}

// Round 5
// 291.373 us; speedup vs baseline: 1.5224x; 1.0666x over previous
//
#include <hip/hip_runtime.h>

#define BB 512
#define TTOK 196
#define DD 256
#define ROWSTRIDE (TTOK * DD)   // 50176 elems between consecutive b rows
#define TCHUNK 14
#define NCHUNK 14               // 196 / 14
#define BK 64                   // k elements per stage
#define NSTAGE (TCHUNK * 4)     // 4 k-stages per t

typedef __attribute__((ext_vector_type(8))) __bf16 bf16x8;
typedef __attribute__((ext_vector_type(4))) float floatx4;
typedef __attribute__((address_space(3))) char* lds_t;
typedef const __attribute__((address_space(1))) void* gas_t;

__device__ __forceinline__ unsigned short f2bf(float f) {
  unsigned int u = __float_as_uint(f);
  u += 0x7FFFu + ((u >> 16) & 1u);   // round-to-nearest-even
  return (unsigned short)(u >> 16);
}

// Kernel 1: per-token L2-normalize + cast to bf16, SAME [B,T,D] layout
// (no transpose -> writes are perfectly sequential). One wave per token.
__global__ __launch_bounds__(256) void k_norm2(const float* __restrict__ text,
                                               const float* __restrict__ visual,
                                               unsigned short* __restrict__ An,
                                               unsigned short* __restrict__ Vn) {
  const float* in = blockIdx.y ? visual : text;
  unsigned short* out = blockIdx.y ? Vn : An;
  int u = blockIdx.x * 4 + threadIdx.y;   // token id
  int lane = threadIdx.x;                 // 0..63
  float4 v = *((const float4*)(in + (size_t)u * DD) + lane);
  float ss = v.x * v.x + v.y * v.y + v.z * v.z + v.w * v.w;
#pragma unroll
  for (int off = 32; off; off >>= 1) ss += __shfl_xor(ss, off, 64);
  float inv = ss > 1e-24f ? 1.0f / sqrtf(ss) : 0.0f;
  ushort4 o;
  o.x = f2bf(v.x * inv);
  o.y = f2bf(v.y * inv);
  o.z = f2bf(v.z * inv);
  o.w = f2bf(v.w * inv);
  *((ushort4*)(out + (size_t)u * DD) + lane) = o;
}

// Kernel 2: fused GEMM+pool, asymmetric 64(b)x128(c) block tile.
// Grid (8,4,NCHUNK)=448 blocks, XCD-swizzled so blocks sharing a z-chunk's
// t-slabs co-locate on one XCD (flat&7 -> xcd; slab stays L2-resident).
// 4 waves: wave tile 32x64 = 2x4 x mfma_f32_16x16x32_bf16. Per stage: stage
// A 64xBK (8KB) + B 128xBK (16KB) via global_load_lds w16, double-buffered
// (48KB LDS, 3 blocks/CU at launch_bounds(256,3)). XOR-granule source
// swizzle keeps LDS stores linear (m104) and ds_read_b128 conflict-free
// (verified 0 conflicts R4). Epilogue: plain float2 partial per chunk.
__global__ __launch_bounds__(256, 3) void k_gemm_pool(
    const unsigned short* __restrict__ An, const unsigned short* __restrict__ Vn,
    float2* __restrict__ partial) {
  __shared__ char smem[49152];
  const int tid = threadIdx.x;
  const int wave = tid >> 6, lane = tid & 63;
  const int wr = wave >> 1, wc = wave & 1;
  const int lm = lane & 15, quad = lane >> 4, l7 = lane & 7;

  // XCD-aware remap: hw flat id (x fastest, round-robin over 8 XCDs by flat&7)
  int flat = blockIdx.x + 8 * blockIdx.y + 32 * blockIdx.z;
  int xcd = flat & 7, j = flat >> 3;
  int virt = xcd * 56 + j;          // 56 = 448/8 blocks per XCD, contiguous work
  int vz = virt >> 5;               // 32 blocks per z-chunk
  int rst = virt & 31;
  int vy = rst >> 3, vx = rst & 7;
  const int row_base = vx * 64;     // b tile (A rows)
  const int col_base = vy * 128;    // c tile (B rows)
  const int t0 = vz * TCHUNK;

  // Staging source offsets (elements, [B,T,D] layout). Linear LDS slot
  // s = q*256+tid -> row r = s>>3 (8 granules/row), slot-granule p = s&7
  // receives global granule g = p ^ (r&7)  (granule = 8 bf16 = 16 B).
  unsigned aoffs[2], boffs[4];
#pragma unroll
  for (int q = 0; q < 2; q++) {
    int s = q * 256 + tid;
    int r = s >> 3;
    int g = (s & 7) ^ (r & 7);
    aoffs[q] = (unsigned)(row_base + r) * ROWSTRIDE + (unsigned)g * 8;
  }
#pragma unroll
  for (int q = 0; q < 4; q++) {
    int s = q * 256 + tid;
    int r = s >> 3;
    int g = (s & 7) ^ (r & 7);
    boffs[q] = (unsigned)(col_base + r) * ROWSTRIDE + (unsigned)g * 8;
  }
  lds_t lds = (lds_t)smem;
  const unsigned ldsoff = (unsigned)tid * 16u;

  floatx4 acc[2][4], sacc[2][4], wacc[2][4];
#pragma unroll
  for (int i = 0; i < 2; i++)
#pragma unroll
    for (int n = 0; n < 4; n++) {
      acc[i][n] = (floatx4){0.f, 0.f, 0.f, 0.f};
      sacc[i][n] = (floatx4){0.f, 0.f, 0.f, 0.f};
      wacc[i][n] = (floatx4){0.f, 0.f, 0.f, 0.f};
    }

  auto issue = [&](int st, int buf) {
    int t = t0 + (st >> 2);
    unsigned kb = (unsigned)(st & 3) * BK;
    const unsigned short* Ab = An + (size_t)t * DD + kb;
    const unsigned short* Bb = Vn + (size_t)t * DD + kb;
    unsigned lb = (unsigned)buf * 24576u + ldsoff;
#pragma unroll
    for (int q = 0; q < 2; q++)
      __builtin_amdgcn_global_load_lds((gas_t)(Ab + aoffs[q]),
                                       (__attribute__((address_space(3))) void*)(lds + lb + (unsigned)q * 4096u),
                                       16, 0, 0);
#pragma unroll
    for (int q = 0; q < 4; q++)
      __builtin_amdgcn_global_load_lds((gas_t)(Bb + boffs[q]),
                                       (__attribute__((address_space(3))) void*)(lds + lb + 8192u + (unsigned)q * 4096u),
                                       16, 0, 0);
  };

  // Fragment row byte-offsets (row stride = BK*2 = 128 B)
  unsigned aRow[2], bRow[4];
#pragma unroll
  for (int i = 0; i < 2; i++) aRow[i] = (unsigned)(wr * 32 + i * 16 + lm) * 128u;
#pragma unroll
  for (int n = 0; n < 4; n++) bRow[n] = (unsigned)(wc * 64 + n * 16 + lm) * 128u;

  issue(0, 0);
  for (int st = 0; st < NSTAGE; ++st) {
    int buf = st & 1;
    __syncthreads();               // drains vmcnt -> buf ready; buf^1 free
    if (st + 1 < NSTAGE) issue(st + 1, buf ^ 1);
    const char* A = smem + buf * 24576;
    const char* B = A + 8192;
#pragma unroll
    for (int k0 = 0; k0 < BK; k0 += 32) {
      unsigned gsw = (unsigned)(((k0 >> 3) + quad) ^ l7) * 16u;
      bf16x8 a[2], b[4];
#pragma unroll
      for (int mi = 0; mi < 2; mi++) a[mi] = *(const bf16x8*)(A + aRow[mi] + gsw);
#pragma unroll
      for (int ni = 0; ni < 4; ni++) b[ni] = *(const bf16x8*)(B + bRow[ni] + gsw);
#pragma unroll
      for (int mi = 0; mi < 2; mi++)
#pragma unroll
        for (int ni = 0; ni < 4; ni++)
          acc[mi][ni] = __builtin_amdgcn_mfma_f32_16x16x32_bf16(a[mi], b[ni], acc[mi][ni], 0, 0, 0);
    }
    if ((st & 3) == 3) {   // end of one t: fold cos tile into pool sums
#pragma unroll
      for (int mi = 0; mi < 2; mi++)
#pragma unroll
        for (int ni = 0; ni < 4; ni++) {
#pragma unroll
          for (int r = 0; r < 4; r++) {
            float c = acc[mi][ni][r];
            float e = __expf(c - 1.0f);
            sacc[mi][ni][r] += e;
            wacc[mi][ni][r] = fmaf(c, e, wacc[mi][ni][r]);
          }
          acc[mi][ni] = (floatx4){0.f, 0.f, 0.f, 0.f};
        }
    }
  }

  // C/D layout (m89-verified): col = lane&15, row = quad*4 + r
  size_t cb = (size_t)vz * (BB * BB);
#pragma unroll
  for (int mi = 0; mi < 2; mi++) {
    int bi = row_base + wr * 32 + mi * 16 + quad * 4;
#pragma unroll
    for (int r = 0; r < 4; r++)
#pragma unroll
      for (int ni = 0; ni < 4; ni++) {
        int ci = col_base + wc * 64 + ni * 16 + lm;
        partial[cb + (size_t)(bi + r) * BB + ci] = make_float2(sacc[mi][ni][r], wacc[mi][ni][r]);
      }
  }
}

// Kernel 3: merge chunk partials -> logits = (w/s)/TEMPERATURE
__global__ __launch_bounds__(256) void k_merge(const float2* __restrict__ partial,
                                               float* __restrict__ logits) {
  int idx = blockIdx.x * 256 + threadIdx.x;
  float s = 0.f, w = 0.f;
#pragma unroll
  for (int ch = 0; ch < NCHUNK; ++ch) {
    float2 p = partial[(size_t)ch * (BB * BB) + idx];
    s += p.x;
    w += p.y;
  }
  logits[idx] = (w / s) * (1.0f / 0.07f);
}

// Kernel 4: per-b row-LSE and col-LSE of logits; contrib[b]=2*L[b,b]-lse_r-lse_c
__global__ __launch_bounds__(256) void k_lse(const float* __restrict__ logits,
                                             float* __restrict__ contrib) {
  int b = blockIdx.x;
  int tid = threadIdx.x;
  __shared__ float sm[4];

  float r0 = logits[(size_t)b * BB + tid];
  float r1 = logits[(size_t)b * BB + tid + 256];
  float c0 = logits[(size_t)tid * BB + b];
  float c1 = logits[((size_t)tid + 256) * BB + b];

  float v = fmaxf(r0, r1);
#pragma unroll
  for (int off = 32; off; off >>= 1) v = fmaxf(v, __shfl_xor(v, off, 64));
  if ((tid & 63) == 0) sm[tid >> 6] = v;
  __syncthreads();
  float mr = fmaxf(fmaxf(sm[0], sm[1]), fmaxf(sm[2], sm[3]));
  __syncthreads();
  v = __expf(r0 - mr) + __expf(r1 - mr);
#pragma unroll
  for (int off = 32; off; off >>= 1) v += __shfl_xor(v, off, 64);
  if ((tid & 63) == 0) sm[tid >> 6] = v;
  __syncthreads();
  float sr = sm[0] + sm[1] + sm[2] + sm[3];
  __syncthreads();
  v = fmaxf(c0, c1);
#pragma unroll
  for (int off = 32; off; off >>= 1) v = fmaxf(v, __shfl_xor(v, off, 64));
  if ((tid & 63) == 0) sm[tid >> 6] = v;
  __syncthreads();
  float mc = fmaxf(fmaxf(sm[0], sm[1]), fmaxf(sm[2], sm[3]));
  __syncthreads();
  v = __expf(c0 - mc) + __expf(c1 - mc);
#pragma unroll
  for (int off = 32; off; off >>= 1) v += __shfl_xor(v, off, 64);
  if ((tid & 63) == 0) sm[tid >> 6] = v;
  __syncthreads();
  float sc = sm[0] + sm[1] + sm[2] + sm[3];

  if (tid == 0) {
    float diag = logits[(size_t)b * BB + b];
    contrib[b] = 2.f * diag - (mr + logf(sr)) - (mc + logf(sc));
  }
}

// Kernel 5: loss = -(1/1024) * sum_b contrib[b]
__global__ __launch_bounds__(256) void k_final(const float* __restrict__ contrib,
                                               float* __restrict__ out) {
  int tid = threadIdx.x;
  float v = contrib[tid] + contrib[tid + 256];
#pragma unroll
  for (int off = 32; off; off >>= 1) v += __shfl_xor(v, off, 64);
  __shared__ float sm[4];
  if ((tid & 63) == 0) sm[tid >> 6] = v;
  __syncthreads();
  if (tid == 0) out[0] = -(sm[0] + sm[1] + sm[2] + sm[3]) * (1.0f / 1024.0f);
}

extern "C" void kernel_launch(void* const* d_in, const int* in_sizes, int n_in,
                              void* d_out, int out_size, void* d_ws, size_t ws_size,
                              hipStream_t stream) {
  const float* text = (const float*)d_in[0];
  const float* visual = (const float*)d_in[1];

  char* ws = (char*)d_ws;
  const size_t szN = (size_t)TTOK * BB * DD * sizeof(unsigned short);   // 51,380,224 B
  const size_t szP = (size_t)NCHUNK * BB * BB * sizeof(float2);         // 29,360,128 B
  unsigned short* An = (unsigned short*)ws;
  unsigned short* Vn = (unsigned short*)(ws + szN);
  float2* partial = (float2*)(ws + 2 * szN);
  float* logits = (float*)(ws + 2 * szN + szP);
  float* contrib = (float*)(ws + 2 * szN + szP + (size_t)BB * BB * sizeof(float));

  dim3 blk1(64, 4);
  k_norm2<<<dim3(BB * TTOK / 4, 2), blk1, 0, stream>>>(text, visual, An, Vn);
  k_gemm_pool<<<dim3(8, 4, NCHUNK), 256, 0, stream>>>(An, Vn, partial);
  k_merge<<<BB * BB / 256, 256, 0, stream>>>(partial, logits);
  k_lse<<<BB, 256, 0, stream>>>(logits, contrib);
  k_final<<<1, 256, 0, stream>>>(contrib, (float*)d_out);
}

// Round 6
// 258.897 us; speedup vs baseline: 1.7134x; 1.1254x over previous
//
#include <hip/hip_runtime.h>

#define BB 512
#define TTOK 196
#define DD 256
#define ROWSTRIDE (TTOK * DD)   // bytes between consecutive b rows (fp8 = 1B/elem)
#define TCHUNK 14
#define NCHUNK 14               // 196 / 14
#define BK 128                  // k bytes (elems) per stage
#define NSTAGE (TCHUNK * 2)     // 2 k-stages per t (D=256)

typedef __attribute__((ext_vector_type(4))) float floatx4;
typedef __attribute__((address_space(3))) char* lds_t;
typedef const __attribute__((address_space(1))) void* gas_t;

// Kernel 1: per-token L2-normalize + cast to OCP fp8 e4m3, [B,T,D] layout.
// One wave per token; lane holds 4 consecutive elems -> packs 1 dword of fp8.
__global__ __launch_bounds__(256) void k_norm2(const float* __restrict__ text,
                                               const float* __restrict__ visual,
                                               unsigned char* __restrict__ An,
                                               unsigned char* __restrict__ Vn) {
  const float* in = blockIdx.y ? visual : text;
  unsigned char* out = blockIdx.y ? Vn : An;
  int u = blockIdx.x * 4 + threadIdx.y;   // token id
  int lane = threadIdx.x;                 // 0..63
  float4 v = *((const float4*)(in + (size_t)u * DD) + lane);
  float ss = v.x * v.x + v.y * v.y + v.z * v.z + v.w * v.w;
#pragma unroll
  for (int off = 32; off; off >>= 1) ss += __shfl_xor(ss, off, 64);
  float inv = ss > 1e-24f ? 1.0f / sqrtf(ss) : 0.0f;
  // v_cvt_pk_fp8_f32: byte0=src0, byte1=src1; word_sel=1 fills high word
  int lo = __builtin_amdgcn_cvt_pk_fp8_f32(v.x * inv, v.y * inv, 0, false);
  int packed = __builtin_amdgcn_cvt_pk_fp8_f32(v.z * inv, v.w * inv, lo, true);
  *((int*)(out + (size_t)u * DD) + lane) = packed;
}

// Kernel 2: fused fp8 GEMM+pool, 64(b)x128(c) block tile, BK=128 (full half-D
// per stage -> 28 stages, half the barriers of the bf16 version).
// Grid (8,4,NCHUNK)=448 blocks, XCD-swizzled (flat&7 -> xcd) so blocks of one
// z-chunk co-locate per XCD and share t-slabs in L2. 4 waves (2x2): wave tile
// 32x64 = 2x4 x mfma_f32_16x16x32_fp8_fp8 per 32-k step. Staging 24KB/stage
// (A 8KB + B 16KB) via global_load_lds w16, double-buffered 48KB -> 3 blk/CU.
// XOR-granule source swizzle (slot p of row r holds granule p^(r&7), granule
// = 16B) keeps LDS stores linear (m104); fragments read as ds_read_b64 at
// slot = ((k0>>4)+(quad>>1))^(row&7), half = quad&1 -> <=2-way aliasing.
__global__ __launch_bounds__(256, 3) void k_gemm_pool(
    const unsigned char* __restrict__ An, const unsigned char* __restrict__ Vn,
    float2* __restrict__ partial) {
  __shared__ char smem[49152];
  const int tid = threadIdx.x;
  const int wave = tid >> 6, lane = tid & 63;
  const int wr = wave >> 1, wc = wave & 1;
  const int lm = lane & 15, quad = lane >> 4, l7 = lane & 7;

  // XCD-aware remap: hw dispatch round-robins flat id over 8 XCDs (flat&7)
  int flat = blockIdx.x + 8 * blockIdx.y + 32 * blockIdx.z;
  int xcd = flat & 7, j = flat >> 3;
  int virt = xcd * 56 + j;          // 56 contiguous work items per XCD
  int vz = virt >> 5;               // 32 blocks per z-chunk
  int rst = virt & 31;
  int vy = rst >> 3, vx = rst & 7;
  const int row_base = vx * 64;     // b tile (A rows)
  const int col_base = vy * 128;    // c tile (B rows)
  const int t0 = vz * TCHUNK;

  // Staging source offsets (bytes). Linear LDS 16B-slot s = q*256+tid ->
  // row r = s>>3 (8 granules/row of 128B), slot p = s&7 holds granule
  // g = p ^ (r&7): source byte = (base+r)*ROWSTRIDE + g*16 (+ t*DD + kb).
  unsigned aoffs[2], boffs[4];
#pragma unroll
  for (int q = 0; q < 2; q++) {
    int s = q * 256 + tid;
    int r = s >> 3;
    int g = (s & 7) ^ (r & 7);
    aoffs[q] = (unsigned)(row_base + r) * ROWSTRIDE + (unsigned)g * 16;
  }
#pragma unroll
  for (int q = 0; q < 4; q++) {
    int s = q * 256 + tid;
    int r = s >> 3;
    int g = (s & 7) ^ (r & 7);
    boffs[q] = (unsigned)(col_base + r) * ROWSTRIDE + (unsigned)g * 16;
  }
  lds_t lds = (lds_t)smem;
  const unsigned ldsoff = (unsigned)tid * 16u;

  floatx4 acc[2][4], sacc[2][4], wacc[2][4];
#pragma unroll
  for (int i = 0; i < 2; i++)
#pragma unroll
    for (int n = 0; n < 4; n++) {
      acc[i][n] = (floatx4){0.f, 0.f, 0.f, 0.f};
      sacc[i][n] = (floatx4){0.f, 0.f, 0.f, 0.f};
      wacc[i][n] = (floatx4){0.f, 0.f, 0.f, 0.f};
    }

  auto issue = [&](int st, int buf) {
    int t = t0 + (st >> 1);
    unsigned kb = (unsigned)(st & 1) * BK;
    const unsigned char* Ab = An + (size_t)t * DD + kb;
    const unsigned char* Bb = Vn + (size_t)t * DD + kb;
    unsigned lb = (unsigned)buf * 24576u + ldsoff;
#pragma unroll
    for (int q = 0; q < 2; q++)
      __builtin_amdgcn_global_load_lds((gas_t)(Ab + aoffs[q]),
                                       (__attribute__((address_space(3))) void*)(lds + lb + (unsigned)q * 4096u),
                                       16, 0, 0);
#pragma unroll
    for (int q = 0; q < 4; q++)
      __builtin_amdgcn_global_load_lds((gas_t)(Bb + boffs[q]),
                                       (__attribute__((address_space(3))) void*)(lds + lb + 8192u + (unsigned)q * 4096u),
                                       16, 0, 0);
  };

  // Fragment row byte-offsets (row stride = BK = 128 B)
  unsigned aRow[2], bRow[4];
#pragma unroll
  for (int i = 0; i < 2; i++) aRow[i] = (unsigned)(wr * 32 + i * 16 + lm) * 128u;
#pragma unroll
  for (int n = 0; n < 4; n++) bRow[n] = (unsigned)(wc * 64 + n * 16 + lm) * 128u;
  const unsigned half8 = (unsigned)(quad & 1) * 8u;

  issue(0, 0);
  for (int st = 0; st < NSTAGE; ++st) {
    int buf = st & 1;
    __syncthreads();               // drains vmcnt -> buf ready; buf^1 free
    if (st + 1 < NSTAGE) issue(st + 1, buf ^ 1);
    const char* A = smem + buf * 24576;
    const char* B = A + 8192;
#pragma unroll
    for (int k0 = 0; k0 < BK; k0 += 32) {
      unsigned slot = (unsigned)(((k0 >> 4) + (quad >> 1)) ^ l7);
      unsigned off = slot * 16u + half8;
      long a[2], b[4];
#pragma unroll
      for (int mi = 0; mi < 2; mi++) a[mi] = *(const long*)(A + aRow[mi] + off);
#pragma unroll
      for (int ni = 0; ni < 4; ni++) b[ni] = *(const long*)(B + bRow[ni] + off);
#pragma unroll
      for (int mi = 0; mi < 2; mi++)
#pragma unroll
        for (int ni = 0; ni < 4; ni++)
          acc[mi][ni] = __builtin_amdgcn_mfma_f32_16x16x32_fp8_fp8(a[mi], b[ni], acc[mi][ni], 0, 0, 0);
    }
    if (st & 1) {   // end of one t (2 stages = full D): fold into pool sums
#pragma unroll
      for (int mi = 0; mi < 2; mi++)
#pragma unroll
        for (int ni = 0; ni < 4; ni++) {
#pragma unroll
          for (int r = 0; r < 4; r++) {
            float c = acc[mi][ni][r];
            float e = __expf(c - 1.0f);
            sacc[mi][ni][r] += e;
            wacc[mi][ni][r] = fmaf(c, e, wacc[mi][ni][r]);
          }
          acc[mi][ni] = (floatx4){0.f, 0.f, 0.f, 0.f};
        }
    }
  }

  // C/D layout (m89-verified, dtype-independent m121-128): col=lane&15,
  // row = quad*4 + r
  size_t cb = (size_t)vz * (BB * BB);
#pragma unroll
  for (int mi = 0; mi < 2; mi++) {
    int bi = row_base + wr * 32 + mi * 16 + quad * 4;
#pragma unroll
    for (int r = 0; r < 4; r++)
#pragma unroll
      for (int ni = 0; ni < 4; ni++) {
        int ci = col_base + wc * 64 + ni * 16 + lm;
        partial[cb + (size_t)(bi + r) * BB + ci] = make_float2(sacc[mi][ni][r], wacc[mi][ni][r]);
      }
  }
}

// Kernel 3: merge chunk partials -> logits = (w/s)/TEMPERATURE
__global__ __launch_bounds__(256) void k_merge(const float2* __restrict__ partial,
                                               float* __restrict__ logits) {
  int idx = blockIdx.x * 256 + threadIdx.x;
  float s = 0.f, w = 0.f;
#pragma unroll
  for (int ch = 0; ch < NCHUNK; ++ch) {
    float2 p = partial[(size_t)ch * (BB * BB) + idx];
    s += p.x;
    w += p.y;
  }
  logits[idx] = (w / s) * (1.0f / 0.07f);
}

// Kernel 4: per-b row-LSE and col-LSE of logits; contrib[b]=2*L[b,b]-lse_r-lse_c
__global__ __launch_bounds__(256) void k_lse(const float* __restrict__ logits,
                                             float* __restrict__ contrib) {
  int b = blockIdx.x;
  int tid = threadIdx.x;
  __shared__ float sm[4];

  float r0 = logits[(size_t)b * BB + tid];
  float r1 = logits[(size_t)b * BB + tid + 256];
  float c0 = logits[(size_t)tid * BB + b];
  float c1 = logits[((size_t)tid + 256) * BB + b];

  float v = fmaxf(r0, r1);
#pragma unroll
  for (int off = 32; off; off >>= 1) v = fmaxf(v, __shfl_xor(v, off, 64));
  if ((tid & 63) == 0) sm[tid >> 6] = v;
  __syncthreads();
  float mr = fmaxf(fmaxf(sm[0], sm[1]), fmaxf(sm[2], sm[3]));
  __syncthreads();
  v = __expf(r0 - mr) + __expf(r1 - mr);
#pragma unroll
  for (int off = 32; off; off >>= 1) v += __shfl_xor(v, off, 64);
  if ((tid & 63) == 0) sm[tid >> 6] = v;
  __syncthreads();
  float sr = sm[0] + sm[1] + sm[2] + sm[3];
  __syncthreads();
  v = fmaxf(c0, c1);
#pragma unroll
  for (int off = 32; off; off >>= 1) v = fmaxf(v, __shfl_xor(v, off, 64));
  if ((tid & 63) == 0) sm[tid >> 6] = v;
  __syncthreads();
  float mc = fmaxf(fmaxf(sm[0], sm[1]), fmaxf(sm[2], sm[3]));
  __syncthreads();
  v = __expf(c0 - mc) + __expf(c1 - mc);
#pragma unroll
  for (int off = 32; off; off >>= 1) v += __shfl_xor(v, off, 64);
  if ((tid & 63) == 0) sm[tid >> 6] = v;
  __syncthreads();
  float sc = sm[0] + sm[1] + sm[2] + sm[3];

  if (tid == 0) {
    float diag = logits[(size_t)b * BB + b];
    contrib[b] = 2.f * diag - (mr + logf(sr)) - (mc + logf(sc));
  }
}

// Kernel 5: loss = -(1/1024) * sum_b contrib[b]
__global__ __launch_bounds__(256) void k_final(const float* __restrict__ contrib,
                                               float* __restrict__ out) {
  int tid = threadIdx.x;
  float v = contrib[tid] + contrib[tid + 256];
#pragma unroll
  for (int off = 32; off; off >>= 1) v += __shfl_xor(v, off, 64);
  __shared__ float sm[4];
  if ((tid & 63) == 0) sm[tid >> 6] = v;
  __syncthreads();
  if (tid == 0) out[0] = -(sm[0] + sm[1] + sm[2] + sm[3]) * (1.0f / 1024.0f);
}

extern "C" void kernel_launch(void* const* d_in, const int* in_sizes, int n_in,
                              void* d_out, int out_size, void* d_ws, size_t ws_size,
                              hipStream_t stream) {
  const float* text = (const float*)d_in[0];
  const float* visual = (const float*)d_in[1];

  char* ws = (char*)d_ws;
  const size_t szN = (size_t)TTOK * BB * DD;                            // 25,690,112 B (fp8)
  const size_t szP = (size_t)NCHUNK * BB * BB * sizeof(float2);         // 29,360,128 B
  unsigned char* An = (unsigned char*)ws;
  unsigned char* Vn = (unsigned char*)(ws + szN);
  float2* partial = (float2*)(ws + 2 * szN);
  float* logits = (float*)(ws + 2 * szN + szP);
  float* contrib = (float*)(ws + 2 * szN + szP + (size_t)BB * BB * sizeof(float));

  dim3 blk1(64, 4);
  k_norm2<<<dim3(BB * TTOK / 4, 2), blk1, 0, stream>>>(text, visual, An, Vn);
  k_gemm_pool<<<dim3(8, 4, NCHUNK), 256, 0, stream>>>(An, Vn, partial);
  k_merge<<<BB * BB / 256, 256, 0, stream>>>(partial, logits);
  k_lse<<<BB, 256, 0, stream>>>(logits, contrib);
  k_final<<<1, 256, 0, stream>>>(contrib, (float*)d_out);
}